// Round 11
// baseline (169.156 us; speedup 1.0000x reference)
//
#include <hip/hip_runtime.h>

typedef unsigned short u16;
typedef __attribute__((ext_vector_type(8))) _Float16 f16x8;
typedef __attribute__((ext_vector_type(4))) float f32x4;

#define MFMA_F16 __builtin_amdgcn_mfma_f32_16x16x32_f16

static __device__ __forceinline__ u16 f2h(float f) {
    return __builtin_bit_cast(u16, (_Float16)f);
}
static __device__ __forceinline__ ushort4 f4_to_h4(const float4 v) {
    ushort4 r;
    r.x = f2h(v.x); r.y = f2h(v.y); r.z = f2h(v.z); r.w = f2h(v.w);
    return r;
}
// async global->LDS, 16B per lane, dest = wave-uniform base + lane*16
static __device__ __forceinline__ void gl16(const u16* g, u16* l) {
    __builtin_amdgcn_global_load_lds(
        (__attribute__((address_space(1))) void*)(g),
        (__attribute__((address_space(3))) void*)(l),
        16, 0, 0);
}

// ---------------------------------------------------------------------------
// Kernel 0: prep_w — W fp32->fp16 and X fp32->fp16 (Xh in d_out scratch).
// (R20, measured good — unchanged.)
// ---------------------------------------------------------------------------
__global__ __launch_bounds__(256) void prep_w(
    const float* __restrict__ wq, const float* __restrict__ wk,
    const float* __restrict__ wv, const float* __restrict__ wo,
    const float* __restrict__ x,
    u16* __restrict__ w4, u16* __restrict__ xh)
{
    const int tid = blockIdx.x * 256 + threadIdx.x;   // 65536 threads
    {
        const float* src = (tid < 16384) ? wq : (tid < 32768) ? wk
                         : (tid < 49152) ? wv : wo;
        ((ushort4*)w4)[tid] = f4_to_h4(((const float4*)src)[tid & 16383]);
    }
#pragma unroll
    for (int i = 0; i < 16; ++i) {
        const int j = i * 65536 + tid;                // 1048576 float4 of X
        ((ushort4*)xh)[j] = f4_to_h4(((const float4*)x)[j]);
    }
}

// ---------------------------------------------------------------------------
// Kernel 1: Q/K/V projection (R20 pipelined version, measured good —
// unchanged): gload_lds dbuf, raw s_barrier + vmcnt(0), XOR swizzle.
// ---------------------------------------------------------------------------
__global__ __launch_bounds__(256, 3) void proj_qkv(
    const u16* __restrict__ Xh, const u16* __restrict__ w4,
    const float* __restrict__ bq, const float* __restrict__ bk,
    const float* __restrict__ bv,
    u16* __restrict__ Qh, u16* __restrict__ Kh, u16* __restrict__ Vt)
{
    const int z = blockIdx.y;
    const u16* __restrict__ W     = w4 + z * 65536;
    const float* __restrict__ bias = (z == 0) ? bq : (z == 1) ? bk : bv;

    const int m0   = blockIdx.x * 64;          // global row (b*2048 + n0)
    const int t    = threadIdx.x;
    const int w    = t >> 6;
    const int lane = t & 63;
    const int quad = lane >> 4;
    const int l16  = lane & 15;

    // [X 2048 u16][W 8192 u16] per buffer x 2 = 20480 u16 (40960 B)
    __shared__ __align__(16) u16 smem[20480];

    const int xrow = t >> 2, xpp = t & 3;
    const unsigned xsrc = (unsigned)((m0 + xrow) * 256
                        + ((xpp ^ ((xrow >> 1) & 3)) * 8));
    unsigned wsrc[4];
#pragma unroll
    for (int i = 0; i < 4; ++i) {
        const int j = i * 256 + t;
        const int row = j >> 2, p = j & 3;
        wsrc[i] = (unsigned)(row * 256 + ((p ^ ((row >> 1) & 3)) * 8));
    }

#define PSTAGE(bufsel, kc_) do {                                             \
        u16* B_ = smem + (bufsel) * 10240;                                   \
        gl16(Xh + xsrc + (unsigned)(kc_) * 32, B_ + w * 512);                \
        _Pragma("unroll")                                                    \
        for (int i_ = 0; i_ < 4; ++i_)                                       \
            gl16(W + wsrc[i_] + (unsigned)(kc_) * 32,                        \
                 B_ + 2048 + i_ * 2048 + w * 512);                           \
    } while (0)

    f32x4 acc[16];
#pragma unroll
    for (int i = 0; i < 16; ++i) acc[i] = f32x4{0.f, 0.f, 0.f, 0.f};

    const int rp = (quad ^ ((l16 >> 1) & 3)) * 8;   // swizzled read offset

    PSTAGE(0, 0);

    for (int kc = 0; kc < 8; ++kc) {
        asm volatile("s_waitcnt vmcnt(0)" ::: "memory");
        __builtin_amdgcn_s_barrier();
        __builtin_amdgcn_sched_barrier(0);
        if (kc + 1 < 8) PSTAGE((kc + 1) & 1, kc + 1);
        __builtin_amdgcn_sched_barrier(0);

        const u16* Xb = smem + (kc & 1) * 10240;
        const u16* Wb = Xb + 2048;

        const f16x8 af = *(const f16x8*)&Xb[(w * 16 + l16) * 32 + rp];
        __builtin_amdgcn_s_setprio(1);
#pragma unroll
        for (int nt = 0; nt < 16; ++nt) {
            const f16x8 bf = *(const f16x8*)&Wb[(nt * 16 + l16) * 32 + rp];
            acc[nt] = MFMA_F16(af, bf, acc[nt], 0, 0, 0);
        }
        __builtin_amdgcn_s_setprio(0);
    }
#undef PSTAGE

    __syncthreads();   // all waves done with LDS before epilogue reuse

    if (z < 2) {
        u16* __restrict__ Y = (z == 0) ? Qh : Kh;
#pragma unroll
        for (int nt = 0; nt < 16; ++nt) {
            const int col = nt * 16 + l16;
            const float bb = bias[col];
#pragma unroll
            for (int r = 0; r < 4; ++r)
                smem[(w * 16 + quad * 4 + r) * 264 + col] = f2h(acc[nt][r] + bb);
        }
        __syncthreads();
#pragma unroll
        for (int i = 0; i < 8; ++i) {
            const int ch = i * 256 + t;
            const int row = ch >> 5, cg = ch & 31;
            *(int4*)&Y[(size_t)(m0 + row) * 256 + cg * 8] =
                *(const int4*)&smem[row * 264 + cg * 8];
        }
    } else {
        const int b  = m0 >> 11;
        const int n0 = m0 & 2047;
#pragma unroll
        for (int nt = 0; nt < 16; ++nt) {
            const int col = nt * 16 + l16;
            const float bb = bias[col];
            ushort4 h4;
            h4.x = f2h(acc[nt][0] + bb);
            h4.y = f2h(acc[nt][1] + bb);
            h4.z = f2h(acc[nt][2] + bb);
            h4.w = f2h(acc[nt][3] + bb);
            *(ushort4*)&smem[col * 72 + w * 16 + quad * 4] = h4;
        }
        __syncthreads();
#pragma unroll
        for (int i = 0; i < 8; ++i) {
            const int ch = i * 256 + t;
            const int row = ch >> 3, cg = ch & 7;
            *(int4*)&Vt[(size_t)b * 524288 + (size_t)row * 2048 + n0 + cg * 8] =
                *(const int4*)&smem[row * 72 + cg * 8];
        }
    }
}

// ---------------------------------------------------------------------------
// Kernel 2: flash attention. R23: LDS diet -> 3 blocks/CU.
// R22 evidence: XCD swizzle made K/V L2-resident (FETCH 70->16MB) with ZERO
// time change -> staging latency fully hidden; limiter is compute+LDS with
// only 8 waves/CU, and occupancy is LDS-capped (64KB dbuf -> 2 blocks).
// Registers cap at ~170/thread (R15/R21 spills) which PERMITS 3 waves/SIMD.
// Diet: K double-buffered (32KB) + V SINGLE-buffered (16KB) = 48KB ->
// 3 blocks/CU (144KB). V latency hides under QK+softmax via counted vmcnt:
//   per tile: QK | softmax | vmcnt(4) [V done; K(t+1) in flight] | barrier |
//             PV | vmcnt(0) | barrier | issue V(t+1) then K(t+2)
// Issue order V-then-K makes vmcnt(4) exact; last tile uses vmcnt(0).
// nz=3 -> grid 768 = exactly 3/CU; z=2 partial -> d_out scratch and
// l[3]/m[3] stats in dead-W/old-lmp slots (R17-proven plumbing).
// XCD-chunked swizzle kept (768%8==0 -> bijective, 96 blocks/XCD).
// ---------------------------------------------------------------------------
__global__ __launch_bounds__(256, 3) void attn(
    const u16* __restrict__ Qh, const u16* __restrict__ Kg,
    const u16* __restrict__ Vt, u16* __restrict__ Op,
    u16* __restrict__ OutS, float* __restrict__ lmpL, float* __restrict__ lmpM)
{
    const int nz = gridDim.z;          // 3
    // XCD-chunked swizzle: linear id -> logical (q0, b, z)
    int lin = blockIdx.x + 32 * (blockIdx.y + 8 * blockIdx.z);
    lin = (lin & 7) * 96 + (lin >> 3);
    const int q0 = (lin & 31) * 64;
    const int b  = (lin >> 5) & 7;
    const int z  = lin >> 8;           // 0..2

    const int tbase = 64 / nz, trem = 64 % nz;     // 21, 1
    const int ntiles = tbase + (z < trem ? 1 : 0); // 22/21/21
    const int tile0  = tbase * z + (z < trem ? z : trem);

    const int t    = threadIdx.x;
    const int w    = t >> 6;
    const int lane = t & 63;
    const int quad = lane >> 4;
    const int l16  = lane & 15;

    // [K0 8192][K1 8192][V 8192] u16 = 49152 B -> 3 blocks/CU
    __shared__ __align__(16) u16 smem[24576];
    u16* Os = smem;                // epilogue reuse: 64 x 264 (16896 u16)

    f16x8 qf[8];
    {
        const size_t qrow = (size_t)(b * 2048 + q0 + w * 16 + l16) * 256;
#pragma unroll
        for (int kc = 0; kc < 8; ++kc)
            qf[kc] = *(const f16x8*)&Qh[qrow + kc * 32 + quad * 8];
    }

    // per-thread staging source bases (tile-invariant, u16 indices)
    unsigned kgb[4], vgb[4];
#pragma unroll
    for (int i = 0; i < 4; ++i) {
        const int j  = w * 4 + i;
        const int r  = 2 * j + (lane >> 5);                 // K LDS row 0..31
        const int pr = ((r >> 2) & 3) * 8 + (r >> 4) * 4 + (r & 3);
        const int c  = lane & 31;                           // 16B chunk in row
        kgb[i] = (unsigned)((b * 2048 + pr) * 256 + ((c ^ (r & 7)) * 8));
        const int rp2 = 8 * j + (lane >> 3);                // V LDS row 0..127
        const int c8 = lane & 7;                            // 16B chunk in row
        const int d  = 2 * rp2 + (c8 >> 2);                 // d-row 0..255
        const int a  = (c8 & 3) ^ (rp2 & 3);                // actual key-chunk
        vgb[i] = (unsigned)(b * 524288 + d * 2048 + a * 8);
    }

#define STAGE_K(bufsel, kt_) do {                                            \
        u16* Kb_ = smem + (bufsel) * 8192;                                   \
        _Pragma("unroll")                                                    \
        for (int i_ = 0; i_ < 4; ++i_)                                       \
            gl16(Kg + kgb[i_] + (unsigned)(kt_) * 256,                       \
                 Kb_ + (w * 4 + i_) * 512);                                  \
    } while (0)
#define STAGE_V(kt_) do {                                                    \
        u16* Vb_ = smem + 16384;                                             \
        _Pragma("unroll")                                                    \
        for (int i_ = 0; i_ < 4; ++i_)                                       \
            gl16(Vt + vgb[i_] + (unsigned)(kt_),                             \
                 Vb_ + (w * 4 + i_) * 512);                                  \
    } while (0)

    f32x4 O[16];
#pragma unroll
    for (int i = 0; i < 16; ++i) O[i] = f32x4{0.f, 0.f, 0.f, 0.f};
    float mrow = -1e30f, lrow = 0.f;

    // V read base (thread-invariant part)
    const int vbase = (l16 >> 1) * 64 + (l16 & 1) * 32
                    + ((quad ^ ((l16 >> 1) & 3)) * 8);

    // prologue: K(0) drained+visible; then V(0), K(1) in flight
    STAGE_K(0, tile0 * 32);
    asm volatile("s_waitcnt vmcnt(0)" ::: "memory");
    __builtin_amdgcn_s_barrier();
    __builtin_amdgcn_sched_barrier(0);
    STAGE_V(tile0 * 32);
    if (ntiles > 1) STAGE_K(1, (tile0 + 1) * 32);
    __builtin_amdgcn_sched_barrier(0);

    for (int it = 0; it < ntiles; ++it) {
        const u16* Kc = smem + (it & 1) * 8192;
        const u16* Vc = smem + 16384;

        f32x4 S[2];
        S[0] = f32x4{0.f, 0.f, 0.f, 0.f};
        S[1] = f32x4{0.f, 0.f, 0.f, 0.f};
        __builtin_amdgcn_s_setprio(1);
#pragma unroll
        for (int kc = 0; kc < 8; ++kc) {
#pragma unroll
            for (int kn = 0; kn < 2; ++kn) {
                const int r2 = kn * 16 + l16;
                const f16x8 kf = *(const f16x8*)
                    &Kc[r2 * 256 + (((kc * 4 + quad) ^ (l16 & 7)) * 8)];
                S[kn] = MFMA_F16(kf, qf[kc], S[kn], 0, 0, 0);
            }
        }
        __builtin_amdgcn_s_setprio(0);

        float mt = fmaxf(fmaxf(fmaxf(S[0][0], S[0][1]), fmaxf(S[0][2], S[0][3])),
                         fmaxf(fmaxf(S[1][0], S[1][1]), fmaxf(S[1][2], S[1][3])));
        mt = fmaxf(mt, __shfl_xor(mt, 16));
        mt = fmaxf(mt, __shfl_xor(mt, 32));
        // T13 defer-max: rescale only when tile max grows past mrow+8.
        if (__any(mt - mrow > 8.f)) {
            const float mnew = fmaxf(mrow, mt);
            const float a = __expf(mrow - mnew);
            lrow *= a;
#pragma unroll
            for (int dv = 0; dv < 16; ++dv)
#pragma unroll
                for (int r = 0; r < 4; ++r) O[dv][r] *= a;
            mrow = mnew;
        }
        f16x8 pfv;
        float s = 0.f;
#pragma unroll
        for (int kn = 0; kn < 2; ++kn)
#pragma unroll
            for (int r = 0; r < 4; ++r) {
                const float e = __expf(S[kn][r] - mrow);
                s += e;
                pfv[kn * 4 + r] = (_Float16)e;
            }
        s += __shfl_xor(s, 16);
        s += __shfl_xor(s, 32);
        lrow += s;

        // V(t) ready? counted: [V(t)(4), K(t+1)(4 if issued)] outstanding
        if (it + 1 < ntiles) {
            asm volatile("s_waitcnt vmcnt(4)" ::: "memory");
        } else {
            asm volatile("s_waitcnt vmcnt(0)" ::: "memory");
        }
        __builtin_amdgcn_s_barrier();        // V writes visible to all waves
        __builtin_amdgcn_sched_barrier(0);

        __builtin_amdgcn_s_setprio(1);
#pragma unroll
        for (int dvt = 0; dvt < 16; ++dvt) {
            const f16x8 vf = *(const f16x8*)&Vc[dvt * 512 + vbase];
            O[dvt] = MFMA_F16(vf, pfv, O[dvt], 0, 0, 0);
        }
        __builtin_amdgcn_s_setprio(0);

        asm volatile("s_waitcnt vmcnt(0)" ::: "memory");  // K(t+1) complete
        __builtin_amdgcn_s_barrier();        // K visible; V buffer free
        __builtin_amdgcn_sched_barrier(0);
        if (it + 1 < ntiles) {
            STAGE_V((tile0 + it + 1) * 32);                // oldest first
            if (it + 2 < ntiles) STAGE_K(it & 1, (tile0 + it + 2) * 32);
        }
        __builtin_amdgcn_sched_barrier(0);
    }
#undef STAGE_K
#undef STAGE_V

    __syncthreads();   // all waves done with last tile before smem reuse
    {
        const float rl = 1.0f / lrow;
#pragma unroll
        for (int dvt = 0; dvt < 16; ++dvt) {
            ushort4 h4;
            h4.x = f2h(O[dvt][0] * rl);
            h4.y = f2h(O[dvt][1] * rl);
            h4.z = f2h(O[dvt][2] * rl);
            h4.w = f2h(O[dvt][3] * rl);
            *(ushort4*)&Os[(w * 16 + l16) * 264 + dvt * 16 + quad * 4] = h4;
        }
        if (quad == 0) {
            const int grow = b * 2048 + q0 + w * 16 + l16;
            lmpL[z * 16384 + grow] = lrow;
            lmpM[z * 16384 + grow] = mrow;
        }
    }
    __syncthreads();

    {
        const int row = t >> 2;
        if (z < 2) {
            u16* __restrict__ Oz = Op + (size_t)z * 4194304;
#pragma unroll
            for (int i = 0; i < 8; ++i) {
                const int chunk = (t & 3) * 8 + i;
                *(int4*)&Oz[(size_t)(b * 2048 + q0 + row) * 256 + chunk * 8] =
                    *(const int4*)&Os[row * 264 + chunk * 8];
            }
        } else {
            // z==2 packed into d_out scratch: row m -> u16[m*512 + 0..255]
            u16* __restrict__ Oz = OutS;
#pragma unroll
            for (int i = 0; i < 8; ++i) {
                const int chunk = (t & 3) * 8 + i;
                *(int4*)&Oz[(size_t)(b * 2048 + q0 + row) * 512 + chunk * 8] =
                    *(const int4*)&Os[row * 264 + chunk * 8];
            }
        }
    }
}

// ---------------------------------------------------------------------------
// Kernel 3: combine 3 partials + out projection + LayerNorm + LeakyReLU.
// R18's proven 3-partial 32-row structure (2 blocks/CU, cross-wave LN merge).
// ---------------------------------------------------------------------------
__global__ __launch_bounds__(256, 2) void outproj_ln(
    const u16* __restrict__ Op, const u16* __restrict__ OutS,
    const float* __restrict__ lmpL, const float* __restrict__ lmpM,
    const u16* __restrict__ Woh, const float* __restrict__ bo,
    const float* __restrict__ gamma, const float* __restrict__ beta,
    float* __restrict__ out)
{
    const int m0   = blockIdx.x * 32;
    const int t    = threadIdx.x;
    const int w    = t >> 6;
    const int rw   = w & 1;        // row-group (16 rows)
    const int cw   = w >> 1;       // col-half (128 cols)
    const int lane = t & 63;
    const int quad = lane >> 4;
    const int l16  = lane & 15;

    __shared__ __align__(16) u16 Ls[32 * 40];
    __shared__ __align__(16) u16 Ws[256 * 40];
    __shared__ _Float16 wls[3][32];
    __shared__ float part[2][16][2][2];   // [rw][row16][cw][{sh,sh2}]

    if (t < 32) {
        const float l0 = lmpL[m0 + t];
        const float l1 = lmpL[16384 + m0 + t];
        const float l2 = lmpL[32768 + m0 + t];
        const float m0v = lmpM[m0 + t];
        const float m1v = lmpM[16384 + m0 + t];
        const float m2v = lmpM[32768 + m0 + t];
        const float mm = fmaxf(fmaxf(m0v, m1v), m2v);
        const float u0 = l0 * __expf(m0v - mm);
        const float u1 = l1 * __expf(m1v - mm);
        const float u2 = l2 * __expf(m2v - mm);
        const float inv = 1.0f / (u0 + u1 + u2);
        wls[0][t] = (_Float16)(u0 * inv);
        wls[1][t] = (_Float16)(u1 * inv);
        wls[2][t] = (_Float16)(u2 * inv);
    }
    __syncthreads();

    f32x4 acc[8];
#pragma unroll
    for (int i = 0; i < 8; ++i) acc[i] = f32x4{0.f, 0.f, 0.f, 0.f};

    for (int kc = 0; kc < 8; ++kc) {
        if (t < 128) {
            const int row = t >> 2, cg = t & 3;
            const size_t off  = (size_t)(m0 + row) * 256 + kc * 32 + cg * 8;
            const size_t offS = (size_t)(m0 + row) * 512 + kc * 32 + cg * 8;
            const f16x8 o0 = __builtin_bit_cast(f16x8, *(const int4*)&Op[off]);
            const f16x8 o1 = __builtin_bit_cast(f16x8, *(const int4*)&Op[4194304 + off]);
            const f16x8 o2 = __builtin_bit_cast(f16x8, *(const int4*)&OutS[offS]);
            const _Float16 w0 = wls[0][row], w1 = wls[1][row], w2 = wls[2][row];
            f16x8 lw;
#pragma unroll
            for (int j = 0; j < 8; ++j)
                lw[j] = o0[j] * w0 + o1[j] * w1 + o2[j] * w2;
            *(int4*)&Ls[row * 40 + cg * 8] = __builtin_bit_cast(int4, lw);
        }
#pragma unroll
        for (int i = 0; i < 4; ++i) {
            const int ch = i * 256 + t;
            const int row = ch >> 2, cg = ch & 3;
            *(int4*)&Ws[row * 40 + cg * 8] =
                *(const int4*)&Woh[(size_t)row * 256 + kc * 32 + cg * 8];
        }
        __syncthreads();

        const f16x8 af = *(const f16x8*)&Ls[(rw * 16 + l16) * 40 + quad * 8];
#pragma unroll
        for (int nt = 0; nt < 8; ++nt) {
            const f16x8 bf = *(const f16x8*)&Ws[((cw * 8 + nt) * 16 + l16) * 40 + quad * 8];
            acc[nt] = MFMA_F16(af, bf, acc[nt], 0, 0, 0);
        }
        __syncthreads();
    }

    float g[8], bt[8], bb[8];
#pragma unroll
    for (int nt = 0; nt < 8; ++nt) {
        const int col = cw * 128 + nt * 16 + l16;
        bb[nt] = bo[col]; g[nt] = gamma[col]; bt[nt] = beta[col];
    }

    float shv[4], sh2v[4];
#pragma unroll
    for (int r = 0; r < 4; ++r) {
        float sh = 0.f, sh2 = 0.f;
#pragma unroll
        for (int nt = 0; nt < 8; ++nt) {
            const float h = acc[nt][r] + bb[nt];
            sh  += h;
            sh2 += h * h;
        }
        sh  += __shfl_xor(sh, 1);  sh  += __shfl_xor(sh, 2);
        sh  += __shfl_xor(sh, 4);  sh  += __shfl_xor(sh, 8);
        sh2 += __shfl_xor(sh2, 1); sh2 += __shfl_xor(sh2, 2);
        sh2 += __shfl_xor(sh2, 4); sh2 += __shfl_xor(sh2, 8);
        shv[r] = sh; sh2v[r] = sh2;
    }
    if (l16 == 0) {
#pragma unroll
        for (int r = 0; r < 4; ++r) {
            part[rw][quad * 4 + r][cw][0] = shv[r];
            part[rw][quad * 4 + r][cw][1] = sh2v[r];
        }
    }
    __syncthreads();

#pragma unroll
    for (int r = 0; r < 4; ++r) {
        const float sh  = shv[r]  + part[rw][quad * 4 + r][cw ^ 1][0];
        const float sh2 = sh2v[r] + part[rw][quad * 4 + r][cw ^ 1][1];
        const float mu  = sh * (1.f / 256.f);
        const float var = fmaxf(sh2 * (1.f / 256.f) - mu * mu, 0.f);
        const float rs  = rsqrtf(var + 1e-5f);
        const size_t row = (size_t)(m0 + rw * 16 + quad * 4 + r) * 256;
#pragma unroll
        for (int nt = 0; nt < 8; ++nt) {
            const float hn = (acc[nt][r] + bb[nt] - mu) * rs * g[nt] + bt[nt];
            out[row + cw * 128 + nt * 16 + l16] = (hn >= 0.f) ? hn : 0.01f * hn;
        }
    }
}

// ---------------------------------------------------------------------------
extern "C" void kernel_launch(void* const* d_in, const int* in_sizes, int n_in,
                              void* d_out, int out_size, void* d_ws, size_t ws_size,
                              hipStream_t stream)
{
    const float* x  = (const float*)d_in[0];
    const float* Wq = (const float*)d_in[1];
    const float* bq = (const float*)d_in[2];
    const float* Wk = (const float*)d_in[3];
    const float* bk = (const float*)d_in[4];
    const float* Wv = (const float*)d_in[5];
    const float* bv = (const float*)d_in[6];
    const float* Wo = (const float*)d_in[7];
    const float* bo = (const float*)d_in[8];
    const float* gm = (const float*)d_in[9];
    const float* bt = (const float*)d_in[10];
    float* out = (float*)d_out;

    // ws layout (u16): [W4 262144][Qh 4.19M][Kh 4.19M][Vt 4.19M][Op 2x4.19M][lmpM]
    // -> identical total d_ws footprint to the baseline.
    // d_out scratch lifecycle: prep_w writes Xh -> proj_qkv reads Xh ->
    // attn overwrites d_out with the z=2 partial -> outproj reads it and
    // writes the final f32 output (rows read before overwritten, block-local).
    // l[3] stats in dead Wq/Wk/Wv half of W4 (384KB, dead after proj);
    // m[3] stats in the old lmp slot.
    u16* W4 = (u16*)d_ws;
    u16* Qh = W4 + 262144;
    u16* Kh = Qh + 4194304;
    u16* Vt = Kh + 4194304;
    u16* Op = Vt + 4194304;
    float* lmpM = (float*)(Op + 2 * 4194304);  // m[3][16384]
    float* lmpL = (float*)W4;                  // l[3][16384] (dead W region)
    u16* Woh = W4 + 196608;
    u16* Xh  = (u16*)d_out;
    u16* OutS = (u16*)d_out;

    prep_w     <<<256,            256, 0, stream>>>(Wq, Wk, Wv, Wo, x, W4, Xh);
    proj_qkv   <<<dim3(256, 3),   256, 0, stream>>>(Xh, W4, bq, bk, bv, Qh, Kh, Vt);
    attn       <<<dim3(32, 8, 3), 256, 0, stream>>>(Qh, Kh, Vt, Op, OutS, lmpL, lmpM);
    outproj_ln <<<512,            256, 0, stream>>>(Op, OutS, lmpL, lmpM, Woh, bo, gm, bt, out);
}

// Round 12
// 167.805 us; speedup vs baseline: 1.0081x; 1.0081x over previous
//
#include <hip/hip_runtime.h>

typedef unsigned short u16;
typedef __attribute__((ext_vector_type(8))) _Float16 f16x8;
typedef __attribute__((ext_vector_type(4))) float f32x4;

#define MFMA_F16 __builtin_amdgcn_mfma_f32_16x16x32_f16

static __device__ __forceinline__ u16 f2h(float f) {
    return __builtin_bit_cast(u16, (_Float16)f);
}
static __device__ __forceinline__ ushort4 f4_to_h4(const float4 v) {
    ushort4 r;
    r.x = f2h(v.x); r.y = f2h(v.y); r.z = f2h(v.z); r.w = f2h(v.w);
    return r;
}
// async global->LDS, 16B per lane, dest = wave-uniform base + lane*16
static __device__ __forceinline__ void gl16(const u16* g, u16* l) {
    __builtin_amdgcn_global_load_lds(
        (__attribute__((address_space(1))) void*)(g),
        (__attribute__((address_space(3))) void*)(l),
        16, 0, 0);
}

// ---------------------------------------------------------------------------
// Kernel 0: prep_w — W fp32->fp16 and X fp32->fp16 (Xh in d_out scratch).
// (R20, measured good — unchanged.)
// ---------------------------------------------------------------------------
__global__ __launch_bounds__(256) void prep_w(
    const float* __restrict__ wq, const float* __restrict__ wk,
    const float* __restrict__ wv, const float* __restrict__ wo,
    const float* __restrict__ x,
    u16* __restrict__ w4, u16* __restrict__ xh)
{
    const int tid = blockIdx.x * 256 + threadIdx.x;   // 65536 threads
    {
        const float* src = (tid < 16384) ? wq : (tid < 32768) ? wk
                         : (tid < 49152) ? wv : wo;
        ((ushort4*)w4)[tid] = f4_to_h4(((const float4*)src)[tid & 16383]);
    }
#pragma unroll
    for (int i = 0; i < 16; ++i) {
        const int j = i * 65536 + tid;                // 1048576 float4 of X
        ((ushort4*)xh)[j] = f4_to_h4(((const float4*)x)[j]);
    }
}

// ---------------------------------------------------------------------------
// Kernel 1: Q/K/V projection (R20 pipelined version, measured good —
// unchanged): gload_lds dbuf, raw s_barrier + vmcnt(0), XOR swizzle.
// ---------------------------------------------------------------------------
__global__ __launch_bounds__(256, 3) void proj_qkv(
    const u16* __restrict__ Xh, const u16* __restrict__ w4,
    const float* __restrict__ bq, const float* __restrict__ bk,
    const float* __restrict__ bv,
    u16* __restrict__ Qh, u16* __restrict__ Kh, u16* __restrict__ Vt)
{
    const int z = blockIdx.y;
    const u16* __restrict__ W     = w4 + z * 65536;
    const float* __restrict__ bias = (z == 0) ? bq : (z == 1) ? bk : bv;

    const int m0   = blockIdx.x * 64;          // global row (b*2048 + n0)
    const int t    = threadIdx.x;
    const int w    = t >> 6;
    const int lane = t & 63;
    const int quad = lane >> 4;
    const int l16  = lane & 15;

    // [X 2048 u16][W 8192 u16] per buffer x 2 = 20480 u16 (40960 B)
    __shared__ __align__(16) u16 smem[20480];

    const int xrow = t >> 2, xpp = t & 3;
    const unsigned xsrc = (unsigned)((m0 + xrow) * 256
                        + ((xpp ^ ((xrow >> 1) & 3)) * 8));
    unsigned wsrc[4];
#pragma unroll
    for (int i = 0; i < 4; ++i) {
        const int j = i * 256 + t;
        const int row = j >> 2, p = j & 3;
        wsrc[i] = (unsigned)(row * 256 + ((p ^ ((row >> 1) & 3)) * 8));
    }

#define PSTAGE(bufsel, kc_) do {                                             \
        u16* B_ = smem + (bufsel) * 10240;                                   \
        gl16(Xh + xsrc + (unsigned)(kc_) * 32, B_ + w * 512);                \
        _Pragma("unroll")                                                    \
        for (int i_ = 0; i_ < 4; ++i_)                                       \
            gl16(W + wsrc[i_] + (unsigned)(kc_) * 32,                        \
                 B_ + 2048 + i_ * 2048 + w * 512);                           \
    } while (0)

    f32x4 acc[16];
#pragma unroll
    for (int i = 0; i < 16; ++i) acc[i] = f32x4{0.f, 0.f, 0.f, 0.f};

    const int rp = (quad ^ ((l16 >> 1) & 3)) * 8;   // swizzled read offset

    PSTAGE(0, 0);

    for (int kc = 0; kc < 8; ++kc) {
        asm volatile("s_waitcnt vmcnt(0)" ::: "memory");
        __builtin_amdgcn_s_barrier();
        __builtin_amdgcn_sched_barrier(0);
        if (kc + 1 < 8) PSTAGE((kc + 1) & 1, kc + 1);
        __builtin_amdgcn_sched_barrier(0);

        const u16* Xb = smem + (kc & 1) * 10240;
        const u16* Wb = Xb + 2048;

        const f16x8 af = *(const f16x8*)&Xb[(w * 16 + l16) * 32 + rp];
        __builtin_amdgcn_s_setprio(1);
#pragma unroll
        for (int nt = 0; nt < 16; ++nt) {
            const f16x8 bf = *(const f16x8*)&Wb[(nt * 16 + l16) * 32 + rp];
            acc[nt] = MFMA_F16(af, bf, acc[nt], 0, 0, 0);
        }
        __builtin_amdgcn_s_setprio(0);
    }
#undef PSTAGE

    __syncthreads();   // all waves done with LDS before epilogue reuse

    if (z < 2) {
        u16* __restrict__ Y = (z == 0) ? Qh : Kh;
#pragma unroll
        for (int nt = 0; nt < 16; ++nt) {
            const int col = nt * 16 + l16;
            const float bb = bias[col];
#pragma unroll
            for (int r = 0; r < 4; ++r)
                smem[(w * 16 + quad * 4 + r) * 264 + col] = f2h(acc[nt][r] + bb);
        }
        __syncthreads();
#pragma unroll
        for (int i = 0; i < 8; ++i) {
            const int ch = i * 256 + t;
            const int row = ch >> 5, cg = ch & 31;
            *(int4*)&Y[(size_t)(m0 + row) * 256 + cg * 8] =
                *(const int4*)&smem[row * 264 + cg * 8];
        }
    } else {
        const int b  = m0 >> 11;
        const int n0 = m0 & 2047;
#pragma unroll
        for (int nt = 0; nt < 16; ++nt) {
            const int col = nt * 16 + l16;
            const float bb = bias[col];
            ushort4 h4;
            h4.x = f2h(acc[nt][0] + bb);
            h4.y = f2h(acc[nt][1] + bb);
            h4.z = f2h(acc[nt][2] + bb);
            h4.w = f2h(acc[nt][3] + bb);
            *(ushort4*)&smem[col * 72 + w * 16 + quad * 4] = h4;
        }
        __syncthreads();
#pragma unroll
        for (int i = 0; i < 8; ++i) {
            const int ch = i * 256 + t;
            const int row = ch >> 3, cg = ch & 7;
            *(int4*)&Vt[(size_t)b * 524288 + (size_t)row * 2048 + n0 + cg * 8] =
                *(const int4*)&smem[row * 72 + cg * 8];
        }
    }
}

// ---------------------------------------------------------------------------
// Kernel 2: flash attention (R23, measured 61.6µs — UNCHANGED).
// K dbuf + V single-buffer (48KB -> 3 blocks/CU), counted vmcnt, nz=3,
// XCD-chunked swizzle, defer-max, setprio.
// ---------------------------------------------------------------------------
__global__ __launch_bounds__(256, 3) void attn(
    const u16* __restrict__ Qh, const u16* __restrict__ Kg,
    const u16* __restrict__ Vt, u16* __restrict__ Op,
    u16* __restrict__ OutS, float* __restrict__ lmpL, float* __restrict__ lmpM)
{
    const int nz = gridDim.z;          // 3
    // XCD-chunked swizzle: linear id -> logical (q0, b, z)
    int lin = blockIdx.x + 32 * (blockIdx.y + 8 * blockIdx.z);
    lin = (lin & 7) * 96 + (lin >> 3);
    const int q0 = (lin & 31) * 64;
    const int b  = (lin >> 5) & 7;
    const int z  = lin >> 8;           // 0..2

    const int tbase = 64 / nz, trem = 64 % nz;     // 21, 1
    const int ntiles = tbase + (z < trem ? 1 : 0); // 22/21/21
    const int tile0  = tbase * z + (z < trem ? z : trem);

    const int t    = threadIdx.x;
    const int w    = t >> 6;
    const int lane = t & 63;
    const int quad = lane >> 4;
    const int l16  = lane & 15;

    // [K0 8192][K1 8192][V 8192] u16 = 49152 B -> 3 blocks/CU
    __shared__ __align__(16) u16 smem[24576];
    u16* Os = smem;                // epilogue reuse: 64 x 264 (16896 u16)

    f16x8 qf[8];
    {
        const size_t qrow = (size_t)(b * 2048 + q0 + w * 16 + l16) * 256;
#pragma unroll
        for (int kc = 0; kc < 8; ++kc)
            qf[kc] = *(const f16x8*)&Qh[qrow + kc * 32 + quad * 8];
    }

    // per-thread staging source bases (tile-invariant, u16 indices)
    unsigned kgb[4], vgb[4];
#pragma unroll
    for (int i = 0; i < 4; ++i) {
        const int j  = w * 4 + i;
        const int r  = 2 * j + (lane >> 5);                 // K LDS row 0..31
        const int pr = ((r >> 2) & 3) * 8 + (r >> 4) * 4 + (r & 3);
        const int c  = lane & 31;                           // 16B chunk in row
        kgb[i] = (unsigned)((b * 2048 + pr) * 256 + ((c ^ (r & 7)) * 8));
        const int rp2 = 8 * j + (lane >> 3);                // V LDS row 0..127
        const int c8 = lane & 7;                            // 16B chunk in row
        const int d  = 2 * rp2 + (c8 >> 2);                 // d-row 0..255
        const int a  = (c8 & 3) ^ (rp2 & 3);                // actual key-chunk
        vgb[i] = (unsigned)(b * 524288 + d * 2048 + a * 8);
    }

#define STAGE_K(bufsel, kt_) do {                                            \
        u16* Kb_ = smem + (bufsel) * 8192;                                   \
        _Pragma("unroll")                                                    \
        for (int i_ = 0; i_ < 4; ++i_)                                       \
            gl16(Kg + kgb[i_] + (unsigned)(kt_) * 256,                       \
                 Kb_ + (w * 4 + i_) * 512);                                  \
    } while (0)
#define STAGE_V(kt_) do {                                                    \
        u16* Vb_ = smem + 16384;                                             \
        _Pragma("unroll")                                                    \
        for (int i_ = 0; i_ < 4; ++i_)                                       \
            gl16(Vt + vgb[i_] + (unsigned)(kt_),                             \
                 Vb_ + (w * 4 + i_) * 512);                                  \
    } while (0)

    f32x4 O[16];
#pragma unroll
    for (int i = 0; i < 16; ++i) O[i] = f32x4{0.f, 0.f, 0.f, 0.f};
    float mrow = -1e30f, lrow = 0.f;

    // V read base (thread-invariant part)
    const int vbase = (l16 >> 1) * 64 + (l16 & 1) * 32
                    + ((quad ^ ((l16 >> 1) & 3)) * 8);

    // prologue: K(0) drained+visible; then V(0), K(1) in flight
    STAGE_K(0, tile0 * 32);
    asm volatile("s_waitcnt vmcnt(0)" ::: "memory");
    __builtin_amdgcn_s_barrier();
    __builtin_amdgcn_sched_barrier(0);
    STAGE_V(tile0 * 32);
    if (ntiles > 1) STAGE_K(1, (tile0 + 1) * 32);
    __builtin_amdgcn_sched_barrier(0);

    for (int it = 0; it < ntiles; ++it) {
        const u16* Kc = smem + (it & 1) * 8192;
        const u16* Vc = smem + 16384;

        f32x4 S[2];
        S[0] = f32x4{0.f, 0.f, 0.f, 0.f};
        S[1] = f32x4{0.f, 0.f, 0.f, 0.f};
        __builtin_amdgcn_s_setprio(1);
#pragma unroll
        for (int kc = 0; kc < 8; ++kc) {
#pragma unroll
            for (int kn = 0; kn < 2; ++kn) {
                const int r2 = kn * 16 + l16;
                const f16x8 kf = *(const f16x8*)
                    &Kc[r2 * 256 + (((kc * 4 + quad) ^ (l16 & 7)) * 8)];
                S[kn] = MFMA_F16(kf, qf[kc], S[kn], 0, 0, 0);
            }
        }
        __builtin_amdgcn_s_setprio(0);

        float mt = fmaxf(fmaxf(fmaxf(S[0][0], S[0][1]), fmaxf(S[0][2], S[0][3])),
                         fmaxf(fmaxf(S[1][0], S[1][1]), fmaxf(S[1][2], S[1][3])));
        mt = fmaxf(mt, __shfl_xor(mt, 16));
        mt = fmaxf(mt, __shfl_xor(mt, 32));
        // T13 defer-max: rescale only when tile max grows past mrow+8.
        if (__any(mt - mrow > 8.f)) {
            const float mnew = fmaxf(mrow, mt);
            const float a = __expf(mrow - mnew);
            lrow *= a;
#pragma unroll
            for (int dv = 0; dv < 16; ++dv)
#pragma unroll
                for (int r = 0; r < 4; ++r) O[dv][r] *= a;
            mrow = mnew;
        }
        f16x8 pfv;
        float s = 0.f;
#pragma unroll
        for (int kn = 0; kn < 2; ++kn)
#pragma unroll
            for (int r = 0; r < 4; ++r) {
                const float e = __expf(S[kn][r] - mrow);
                s += e;
                pfv[kn * 4 + r] = (_Float16)e;
            }
        s += __shfl_xor(s, 16);
        s += __shfl_xor(s, 32);
        lrow += s;

        // V(t) ready? counted: [V(t)(4), K(t+1)(4 if issued)] outstanding
        if (it + 1 < ntiles) {
            asm volatile("s_waitcnt vmcnt(4)" ::: "memory");
        } else {
            asm volatile("s_waitcnt vmcnt(0)" ::: "memory");
        }
        __builtin_amdgcn_s_barrier();        // V writes visible to all waves
        __builtin_amdgcn_sched_barrier(0);

        __builtin_amdgcn_s_setprio(1);
#pragma unroll
        for (int dvt = 0; dvt < 16; ++dvt) {
            const f16x8 vf = *(const f16x8*)&Vc[dvt * 512 + vbase];
            O[dvt] = MFMA_F16(vf, pfv, O[dvt], 0, 0, 0);
        }
        __builtin_amdgcn_s_setprio(0);

        asm volatile("s_waitcnt vmcnt(0)" ::: "memory");  // K(t+1) complete
        __builtin_amdgcn_s_barrier();        // K visible; V buffer free
        __builtin_amdgcn_sched_barrier(0);
        if (it + 1 < ntiles) {
            STAGE_V((tile0 + it + 1) * 32);                // oldest first
            if (it + 2 < ntiles) STAGE_K(it & 1, (tile0 + it + 2) * 32);
        }
        __builtin_amdgcn_sched_barrier(0);
    }
#undef STAGE_K
#undef STAGE_V

    __syncthreads();   // all waves done with last tile before smem reuse
    {
        const float rl = 1.0f / lrow;
#pragma unroll
        for (int dvt = 0; dvt < 16; ++dvt) {
            ushort4 h4;
            h4.x = f2h(O[dvt][0] * rl);
            h4.y = f2h(O[dvt][1] * rl);
            h4.z = f2h(O[dvt][2] * rl);
            h4.w = f2h(O[dvt][3] * rl);
            *(ushort4*)&Os[(w * 16 + l16) * 264 + dvt * 16 + quad * 4] = h4;
        }
        if (quad == 0) {
            const int grow = b * 2048 + q0 + w * 16 + l16;
            lmpL[z * 16384 + grow] = lrow;
            lmpM[z * 16384 + grow] = mrow;
        }
    }
    __syncthreads();

    {
        const int row = t >> 2;
        if (z < 2) {
            u16* __restrict__ Oz = Op + (size_t)z * 4194304;
#pragma unroll
            for (int i = 0; i < 8; ++i) {
                const int chunk = (t & 3) * 8 + i;
                *(int4*)&Oz[(size_t)(b * 2048 + q0 + row) * 256 + chunk * 8] =
                    *(const int4*)&Os[row * 264 + chunk * 8];
            }
        } else {
            // z==2 packed into d_out scratch: row m -> u16[m*512 + 0..255]
            u16* __restrict__ Oz = OutS;
#pragma unroll
            for (int i = 0; i < 8; ++i) {
                const int chunk = (t & 3) * 8 + i;
                *(int4*)&Oz[(size_t)(b * 2048 + q0 + row) * 512 + chunk * 8] =
                    *(const int4*)&Os[row * 264 + chunk * 8];
            }
        }
    }
}

// ---------------------------------------------------------------------------
// Kernel 3: combine 3 partials + out projection + LayerNorm + LeakyReLU.
// R24: rebuilt on the R19/R20 pipeline template. W staged via gload_lds
// double-buffer (2x16KB) with the proj-proven XOR swizzle; partials loaded
// to registers one kc ahead and combined AFTER the MFMA block into a
// double-buffered Ls (2x2KB); ONE raw s_barrier + vmcnt(0) per kc (was two
// __syncthreads with full drains). LDS 36.5KB, acc[8]=32 regs -> no spill
// risk (outproj has far more reg headroom than attn's R15 failure).
// ---------------------------------------------------------------------------
__global__ __launch_bounds__(256, 2) void outproj_ln(
    const u16* __restrict__ Op, const u16* __restrict__ OutS,
    const float* __restrict__ lmpL, const float* __restrict__ lmpM,
    const u16* __restrict__ Woh, const float* __restrict__ bo,
    const float* __restrict__ gamma, const float* __restrict__ beta,
    float* __restrict__ out)
{
    const int m0   = blockIdx.x * 32;
    const int t    = threadIdx.x;
    const int w    = t >> 6;
    const int rw   = w & 1;        // row-group (16 rows)
    const int cw   = w >> 1;       // col-half (128 cols)
    const int lane = t & 63;
    const int quad = lane >> 4;
    const int l16  = lane & 15;

    // [Ws0 8192][Ws1 8192][Ls0 1024][Ls1 1024] u16 = 36864 B
    __shared__ __align__(16) u16 smem[18432];
    __shared__ _Float16 wls[3][32];
    __shared__ float part[2][16][2][2];   // [rw][row16][cw][{sh,sh2}]

    // W staging source indices (tile-invariant, u16; proj-proven swizzle)
    unsigned wsrc[4];
#pragma unroll
    for (int i = 0; i < 4; ++i) {
        const int j = i * 256 + t;
        const int row = j >> 2, p = j & 3;
        wsrc[i] = (unsigned)(row * 256 + ((p ^ ((row >> 1) & 3)) * 8));
    }
#define OSTAGE_W(bufsel, kc_) do {                                           \
        u16* B_ = smem + (bufsel) * 8192;                                    \
        _Pragma("unroll")                                                    \
        for (int i_ = 0; i_ < 4; ++i_)                                       \
            gl16(Woh + wsrc[i_] + (unsigned)(kc_) * 32,                      \
                 B_ + i_ * 2048 + w * 512);                                  \
    } while (0)

    const int prow = t >> 2, pcg = t & 3;   // partial row/chunk (t<128 active)
    const unsigned lsw = (unsigned)(prow * 32 + ((pcg ^ ((prow >> 1) & 3)) * 8));

    // prologue: stage W(0) + load partials(0) (latency overlaps wls barrier)
    OSTAGE_W(0, 0);
    int4 po0, po1, po2;
    if (t < 128) {
        const size_t off  = (size_t)(m0 + prow) * 256 + pcg * 8;
        const size_t offS = (size_t)(m0 + prow) * 512 + pcg * 8;
        po0 = *(const int4*)&Op[off];
        po1 = *(const int4*)&Op[4194304 + off];
        po2 = *(const int4*)&OutS[offS];
    }

    if (t < 32) {
        const float l0 = lmpL[m0 + t];
        const float l1 = lmpL[16384 + m0 + t];
        const float l2 = lmpL[32768 + m0 + t];
        const float m0v = lmpM[m0 + t];
        const float m1v = lmpM[16384 + m0 + t];
        const float m2v = lmpM[32768 + m0 + t];
        const float mm = fmaxf(fmaxf(m0v, m1v), m2v);
        const float u0 = l0 * __expf(m0v - mm);
        const float u1 = l1 * __expf(m1v - mm);
        const float u2 = l2 * __expf(m2v - mm);
        const float inv = 1.0f / (u0 + u1 + u2);
        wls[0][t] = (_Float16)(u0 * inv);
        wls[1][t] = (_Float16)(u1 * inv);
        wls[2][t] = (_Float16)(u2 * inv);
    }
    __syncthreads();   // wls visible (prologue-only full drain is fine)

    if (t < 128) {
        const _Float16 w0 = wls[0][prow], w1 = wls[1][prow], w2 = wls[2][prow];
        const f16x8 o0 = __builtin_bit_cast(f16x8, po0);
        const f16x8 o1 = __builtin_bit_cast(f16x8, po1);
        const f16x8 o2 = __builtin_bit_cast(f16x8, po2);
        f16x8 lw;
#pragma unroll
        for (int j = 0; j < 8; ++j)
            lw[j] = o0[j] * w0 + o1[j] * w1 + o2[j] * w2;
        *(int4*)&smem[16384 + lsw] = __builtin_bit_cast(int4, lw);   // Ls0
    }

    f32x4 acc[8];
#pragma unroll
    for (int i = 0; i < 8; ++i) acc[i] = f32x4{0.f, 0.f, 0.f, 0.f};

    const int rp = (quad ^ ((l16 >> 1) & 3)) * 8;   // swizzled read offset

    for (int kc = 0; kc < 8; ++kc) {
        asm volatile("s_waitcnt vmcnt(0)" ::: "memory");
        __builtin_amdgcn_s_barrier();       // W(kc) in LDS; Ls(kc) visible
        __builtin_amdgcn_sched_barrier(0);
        if (kc + 1 < 8) {
            OSTAGE_W((kc + 1) & 1, kc + 1);
            if (t < 128) {
                const size_t off  = (size_t)(m0 + prow) * 256 + (kc + 1) * 32 + pcg * 8;
                const size_t offS = (size_t)(m0 + prow) * 512 + (kc + 1) * 32 + pcg * 8;
                po0 = *(const int4*)&Op[off];
                po1 = *(const int4*)&Op[4194304 + off];
                po2 = *(const int4*)&OutS[offS];
            }
        }
        __builtin_amdgcn_sched_barrier(0);

        const u16* Wb = smem + (kc & 1) * 8192;
        const u16* Lb = smem + 16384 + (kc & 1) * 1024;

        const f16x8 af = *(const f16x8*)&Lb[(rw * 16 + l16) * 32 + rp];
        __builtin_amdgcn_s_setprio(1);
#pragma unroll
        for (int nt = 0; nt < 8; ++nt) {
            const f16x8 bf = *(const f16x8*)&Wb[((cw * 8 + nt) * 16 + l16) * 32 + rp];
            acc[nt] = MFMA_F16(af, bf, acc[nt], 0, 0, 0);
        }
        __builtin_amdgcn_s_setprio(0);

        if (kc + 1 < 8 && t < 128) {
            const _Float16 w0 = wls[0][prow], w1 = wls[1][prow], w2 = wls[2][prow];
            const f16x8 o0 = __builtin_bit_cast(f16x8, po0);
            const f16x8 o1 = __builtin_bit_cast(f16x8, po1);
            const f16x8 o2 = __builtin_bit_cast(f16x8, po2);
            f16x8 lw;
#pragma unroll
            for (int j = 0; j < 8; ++j)
                lw[j] = o0[j] * w0 + o1[j] * w1 + o2[j] * w2;
            *(int4*)&smem[16384 + ((kc + 1) & 1) * 1024 + lsw] =
                __builtin_bit_cast(int4, lw);
        }
    }
#undef OSTAGE_W

    float g[8], bt[8], bb[8];
#pragma unroll
    for (int nt = 0; nt < 8; ++nt) {
        const int col = cw * 128 + nt * 16 + l16;
        bb[nt] = bo[col]; g[nt] = gamma[col]; bt[nt] = beta[col];
    }

    float shv[4], sh2v[4];
#pragma unroll
    for (int r = 0; r < 4; ++r) {
        float sh = 0.f, sh2 = 0.f;
#pragma unroll
        for (int nt = 0; nt < 8; ++nt) {
            const float h = acc[nt][r] + bb[nt];
            sh  += h;
            sh2 += h * h;
        }
        sh  += __shfl_xor(sh, 1);  sh  += __shfl_xor(sh, 2);
        sh  += __shfl_xor(sh, 4);  sh  += __shfl_xor(sh, 8);
        sh2 += __shfl_xor(sh2, 1); sh2 += __shfl_xor(sh2, 2);
        sh2 += __shfl_xor(sh2, 4); sh2 += __shfl_xor(sh2, 8);
        shv[r] = sh; sh2v[r] = sh2;
    }
    if (l16 == 0) {
#pragma unroll
        for (int r = 0; r < 4; ++r) {
            part[rw][quad * 4 + r][cw][0] = shv[r];
            part[rw][quad * 4 + r][cw][1] = sh2v[r];
        }
    }
    __syncthreads();

#pragma unroll
    for (int r = 0; r < 4; ++r) {
        const float sh  = shv[r]  + part[rw][quad * 4 + r][cw ^ 1][0];
        const float sh2 = sh2v[r] + part[rw][quad * 4 + r][cw ^ 1][1];
        const float mu  = sh * (1.f / 256.f);
        const float var = fmaxf(sh2 * (1.f / 256.f) - mu * mu, 0.f);
        const float rs  = rsqrtf(var + 1e-5f);
        const size_t row = (size_t)(m0 + rw * 16 + quad * 4 + r) * 256;
#pragma unroll
        for (int nt = 0; nt < 8; ++nt) {
            const float hn = (acc[nt][r] + bb[nt] - mu) * rs * g[nt] + bt[nt];
            out[row + cw * 128 + nt * 16 + l16] = (hn >= 0.f) ? hn : 0.01f * hn;
        }
    }
}

// ---------------------------------------------------------------------------
extern "C" void kernel_launch(void* const* d_in, const int* in_sizes, int n_in,
                              void* d_out, int out_size, void* d_ws, size_t ws_size,
                              hipStream_t stream)
{
    const float* x  = (const float*)d_in[0];
    const float* Wq = (const float*)d_in[1];
    const float* bq = (const float*)d_in[2];
    const float* Wk = (const float*)d_in[3];
    const float* bk = (const float*)d_in[4];
    const float* Wv = (const float*)d_in[5];
    const float* bv = (const float*)d_in[6];
    const float* Wo = (const float*)d_in[7];
    const float* bo = (const float*)d_in[8];
    const float* gm = (const float*)d_in[9];
    const float* bt = (const float*)d_in[10];
    float* out = (float*)d_out;

    // ws layout (u16): [W4 262144][Qh 4.19M][Kh 4.19M][Vt 4.19M][Op 2x4.19M][lmpM]
    // -> identical total d_ws footprint to the baseline.
    // d_out scratch lifecycle: prep_w writes Xh -> proj_qkv reads Xh ->
    // attn overwrites d_out with the z=2 partial -> outproj reads it and
    // writes the final f32 output (rows read before overwritten, block-local).
    // l[3] stats in dead Wq/Wk/Wv half of W4 (384KB, dead after proj);
    // m[3] stats in the old lmp slot.
    u16* W4 = (u16*)d_ws;
    u16* Qh = W4 + 262144;
    u16* Kh = Qh + 4194304;
    u16* Vt = Kh + 4194304;
    u16* Op = Vt + 4194304;
    float* lmpM = (float*)(Op + 2 * 4194304);  // m[3][16384]
    float* lmpL = (float*)W4;                  // l[3][16384] (dead W region)
    u16* Woh = W4 + 196608;
    u16* Xh  = (u16*)d_out;
    u16* OutS = (u16*)d_out;

    prep_w     <<<256,            256, 0, stream>>>(Wq, Wk, Wv, Wo, x, W4, Xh);
    proj_qkv   <<<dim3(256, 3),   256, 0, stream>>>(Xh, W4, bq, bk, bv, Qh, Kh, Vt);
    attn       <<<dim3(32, 8, 3), 256, 0, stream>>>(Qh, Kh, Vt, Op, OutS, lmpL, lmpM);
    outproj_ln <<<512,            256, 0, stream>>>(Op, OutS, lmpL, lmpM, Woh, bo, gm, bt, out);
}

// Round 13
// 164.980 us; speedup vs baseline: 1.0253x; 1.0171x over previous
//
#include <hip/hip_runtime.h>

typedef unsigned short u16;
typedef __attribute__((ext_vector_type(8))) _Float16 f16x8;
typedef __attribute__((ext_vector_type(4))) float f32x4;

#define MFMA_F16 __builtin_amdgcn_mfma_f32_16x16x32_f16

static __device__ __forceinline__ u16 f2h(float f) {
    return __builtin_bit_cast(u16, (_Float16)f);
}
static __device__ __forceinline__ ushort4 f4_to_h4(const float4 v) {
    ushort4 r;
    r.x = f2h(v.x); r.y = f2h(v.y); r.z = f2h(v.z); r.w = f2h(v.w);
    return r;
}
// async global->LDS, 16B per lane, dest = wave-uniform base + lane*16
static __device__ __forceinline__ void gl16(const u16* g, u16* l) {
    __builtin_amdgcn_global_load_lds(
        (__attribute__((address_space(1))) void*)(g),
        (__attribute__((address_space(3))) void*)(l),
        16, 0, 0);
}
static __device__ __forceinline__ void gl16f(const float* g, u16* l) {
    __builtin_amdgcn_global_load_lds(
        (__attribute__((address_space(1))) void*)(g),
        (__attribute__((address_space(3))) void*)(l),
        16, 0, 0);
}

// ---------------------------------------------------------------------------
// Kernel 0: prep_w — R25: W-only fp32->fp16 (Xh pass eliminated; proj now
// stages fp32 X directly). Traffic 26MB -> 2MB.
// ---------------------------------------------------------------------------
__global__ __launch_bounds__(256) void prep_w(
    const float* __restrict__ wq, const float* __restrict__ wk,
    const float* __restrict__ wv, const float* __restrict__ wo,
    u16* __restrict__ w4)
{
    const int tid = blockIdx.x * 256 + threadIdx.x;   // 16384 threads
    for (int i = tid; i < 65536; i += 16384) {
        const float* src = (i < 16384) ? wq : (i < 32768) ? wk
                         : (i < 49152) ? wv : wo;
        ((ushort4*)w4)[i] = f4_to_h4(((const float4*)src)[i & 16383]);
    }
}

// ---------------------------------------------------------------------------
// Kernel 1: Q/K/V projection. R25: stages fp32 X directly via gload_lds
// (was fp16 Xh from a prep pass): X tile 8KB/buffer, pair-XOR swizzle
// (position pair P holds data pair P^(row&3); read at q^(row&3)) applied
// on BOTH sides (rule 21); f32->f16 convert at af-build (8 cvts/wave/kc).
// W staging unchanged (fp16 from W4). LDS: (X 4096 + W 8192) x 2 = 24576
// u16 = 49152 B -> 3 blocks/CU, same as before. Pipeline structure (R20):
// gload_lds dbuf, raw s_barrier + vmcnt(0), setprio.
// ---------------------------------------------------------------------------
__global__ __launch_bounds__(256, 3) void proj_qkv(
    const float* __restrict__ X, const u16* __restrict__ w4,
    const float* __restrict__ bq, const float* __restrict__ bk,
    const float* __restrict__ bv,
    u16* __restrict__ Qh, u16* __restrict__ Kh, u16* __restrict__ Vt)
{
    const int z = blockIdx.y;
    const u16* __restrict__ W     = w4 + z * 65536;
    const float* __restrict__ bias = (z == 0) ? bq : (z == 1) ? bk : bv;

    const int m0   = blockIdx.x * 64;          // global row (b*2048 + n0)
    const int t    = threadIdx.x;
    const int w    = t >> 6;
    const int lane = t & 63;
    const int quad = lane >> 4;
    const int l16  = lane & 15;

    // per buffer: [X 4096 u16 (= 8KB f32)][W 8192 u16] ; x2 buffers
    __shared__ __align__(16) u16 smem[24576];

    // X staging source float-indices (tile-invariant): thread ch=i*256+t
    // covers (row, p); position (row,p) holds data chunk ((p>>1)^(row&3))*2+(p&1)
    unsigned xsrcF[2];
#pragma unroll
    for (int i = 0; i < 2; ++i) {
        const int ch = i * 256 + t;
        const int row = ch >> 3, p = ch & 7;
        const int dchunk = (((p >> 1) ^ (row & 3)) * 2 + (p & 1));
        xsrcF[i] = (unsigned)((m0 + row) * 256 + dchunk * 4);
    }
    unsigned wsrc[4];
#pragma unroll
    for (int i = 0; i < 4; ++i) {
        const int j = i * 256 + t;
        const int row = j >> 2, p = j & 3;
        wsrc[i] = (unsigned)(row * 256 + ((p ^ ((row >> 1) & 3)) * 8));
    }

#define PSTAGE(bufsel, kc_) do {                                             \
        u16* B_ = smem + (bufsel) * 12288;                                   \
        _Pragma("unroll")                                                    \
        for (int i_ = 0; i_ < 2; ++i_)                                       \
            gl16f(X + xsrcF[i_] + (unsigned)(kc_) * 32,                      \
                  B_ + i_ * 2048 + w * 512);                                 \
        _Pragma("unroll")                                                    \
        for (int i_ = 0; i_ < 4; ++i_)                                       \
            gl16(W + wsrc[i_] + (unsigned)(kc_) * 32,                        \
                 B_ + 4096 + i_ * 2048 + w * 512);                           \
    } while (0)

    f32x4 acc[16];
#pragma unroll
    for (int i = 0; i < 16; ++i) acc[i] = f32x4{0.f, 0.f, 0.f, 0.f};

    const int rp = (quad ^ ((l16 >> 1) & 3)) * 8;   // W swizzled read offset
    const int xo = (w * 16 + l16) * 64 + ((quad ^ (l16 & 3)) * 16); // X read

    PSTAGE(0, 0);

    for (int kc = 0; kc < 8; ++kc) {
        asm volatile("s_waitcnt vmcnt(0)" ::: "memory");
        __builtin_amdgcn_s_barrier();
        __builtin_amdgcn_sched_barrier(0);
        if (kc + 1 < 8) PSTAGE((kc + 1) & 1, kc + 1);
        __builtin_amdgcn_sched_barrier(0);

        const u16* Xb = smem + (kc & 1) * 12288;
        const u16* Wb = Xb + 4096;

        const float* Xf = (const float*)&Xb[xo];
        const float4 xa = ((const float4*)Xf)[0];
        const float4 xc = ((const float4*)Xf)[1];
        f16x8 af;
        af[0] = (_Float16)xa.x; af[1] = (_Float16)xa.y;
        af[2] = (_Float16)xa.z; af[3] = (_Float16)xa.w;
        af[4] = (_Float16)xc.x; af[5] = (_Float16)xc.y;
        af[6] = (_Float16)xc.z; af[7] = (_Float16)xc.w;

        __builtin_amdgcn_s_setprio(1);
#pragma unroll
        for (int nt = 0; nt < 16; ++nt) {
            const f16x8 bf = *(const f16x8*)&Wb[(nt * 16 + l16) * 32 + rp];
            acc[nt] = MFMA_F16(af, bf, acc[nt], 0, 0, 0);
        }
        __builtin_amdgcn_s_setprio(0);
    }
#undef PSTAGE

    __syncthreads();   // all waves done with LDS before epilogue reuse

    if (z < 2) {
        u16* __restrict__ Y = (z == 0) ? Qh : Kh;
#pragma unroll
        for (int nt = 0; nt < 16; ++nt) {
            const int col = nt * 16 + l16;
            const float bb = bias[col];
#pragma unroll
            for (int r = 0; r < 4; ++r)
                smem[(w * 16 + quad * 4 + r) * 264 + col] = f2h(acc[nt][r] + bb);
        }
        __syncthreads();
#pragma unroll
        for (int i = 0; i < 8; ++i) {
            const int ch = i * 256 + t;
            const int row = ch >> 5, cg = ch & 31;
            *(int4*)&Y[(size_t)(m0 + row) * 256 + cg * 8] =
                *(const int4*)&smem[row * 264 + cg * 8];
        }
    } else {
        const int b  = m0 >> 11;
        const int n0 = m0 & 2047;
#pragma unroll
        for (int nt = 0; nt < 16; ++nt) {
            const int col = nt * 16 + l16;
            const float bb = bias[col];
            ushort4 h4;
            h4.x = f2h(acc[nt][0] + bb);
            h4.y = f2h(acc[nt][1] + bb);
            h4.z = f2h(acc[nt][2] + bb);
            h4.w = f2h(acc[nt][3] + bb);
            *(ushort4*)&smem[col * 72 + w * 16 + quad * 4] = h4;
        }
        __syncthreads();
#pragma unroll
        for (int i = 0; i < 8; ++i) {
            const int ch = i * 256 + t;
            const int row = ch >> 3, cg = ch & 7;
            *(int4*)&Vt[(size_t)b * 524288 + (size_t)row * 2048 + n0 + cg * 8] =
                *(const int4*)&smem[row * 72 + cg * 8];
        }
    }
}

// ---------------------------------------------------------------------------
// Kernel 2: flash attention (R23, measured 61.6µs — UNCHANGED).
// K dbuf + V single-buffer (48KB -> 3 blocks/CU), counted vmcnt, nz=3,
// XCD-chunked swizzle, defer-max, setprio.
// ---------------------------------------------------------------------------
__global__ __launch_bounds__(256, 3) void attn(
    const u16* __restrict__ Qh, const u16* __restrict__ Kg,
    const u16* __restrict__ Vt, u16* __restrict__ Op,
    u16* __restrict__ OutS, float* __restrict__ lmpL, float* __restrict__ lmpM)
{
    const int nz = gridDim.z;          // 3
    // XCD-chunked swizzle: linear id -> logical (q0, b, z)
    int lin = blockIdx.x + 32 * (blockIdx.y + 8 * blockIdx.z);
    lin = (lin & 7) * 96 + (lin >> 3);
    const int q0 = (lin & 31) * 64;
    const int b  = (lin >> 5) & 7;
    const int z  = lin >> 8;           // 0..2

    const int tbase = 64 / nz, trem = 64 % nz;     // 21, 1
    const int ntiles = tbase + (z < trem ? 1 : 0); // 22/21/21
    const int tile0  = tbase * z + (z < trem ? z : trem);

    const int t    = threadIdx.x;
    const int w    = t >> 6;
    const int lane = t & 63;
    const int quad = lane >> 4;
    const int l16  = lane & 15;

    // [K0 8192][K1 8192][V 8192] u16 = 49152 B -> 3 blocks/CU
    __shared__ __align__(16) u16 smem[24576];
    u16* Os = smem;                // epilogue reuse: 64 x 264 (16896 u16)

    f16x8 qf[8];
    {
        const size_t qrow = (size_t)(b * 2048 + q0 + w * 16 + l16) * 256;
#pragma unroll
        for (int kc = 0; kc < 8; ++kc)
            qf[kc] = *(const f16x8*)&Qh[qrow + kc * 32 + quad * 8];
    }

    // per-thread staging source bases (tile-invariant, u16 indices)
    unsigned kgb[4], vgb[4];
#pragma unroll
    for (int i = 0; i < 4; ++i) {
        const int j  = w * 4 + i;
        const int r  = 2 * j + (lane >> 5);                 // K LDS row 0..31
        const int pr = ((r >> 2) & 3) * 8 + (r >> 4) * 4 + (r & 3);
        const int c  = lane & 31;                           // 16B chunk in row
        kgb[i] = (unsigned)((b * 2048 + pr) * 256 + ((c ^ (r & 7)) * 8));
        const int rp2 = 8 * j + (lane >> 3);                // V LDS row 0..127
        const int c8 = lane & 7;                            // 16B chunk in row
        const int d  = 2 * rp2 + (c8 >> 2);                 // d-row 0..255
        const int a  = (c8 & 3) ^ (rp2 & 3);                // actual key-chunk
        vgb[i] = (unsigned)(b * 524288 + d * 2048 + a * 8);
    }

#define STAGE_K(bufsel, kt_) do {                                            \
        u16* Kb_ = smem + (bufsel) * 8192;                                   \
        _Pragma("unroll")                                                    \
        for (int i_ = 0; i_ < 4; ++i_)                                       \
            gl16(Kg + kgb[i_] + (unsigned)(kt_) * 256,                       \
                 Kb_ + (w * 4 + i_) * 512);                                  \
    } while (0)
#define STAGE_V(kt_) do {                                                    \
        u16* Vb_ = smem + 16384;                                             \
        _Pragma("unroll")                                                    \
        for (int i_ = 0; i_ < 4; ++i_)                                       \
            gl16(Vt + vgb[i_] + (unsigned)(kt_),                             \
                 Vb_ + (w * 4 + i_) * 512);                                  \
    } while (0)

    f32x4 O[16];
#pragma unroll
    for (int i = 0; i < 16; ++i) O[i] = f32x4{0.f, 0.f, 0.f, 0.f};
    float mrow = -1e30f, lrow = 0.f;

    // V read base (thread-invariant part)
    const int vbase = (l16 >> 1) * 64 + (l16 & 1) * 32
                    + ((quad ^ ((l16 >> 1) & 3)) * 8);

    // prologue: K(0) drained+visible; then V(0), K(1) in flight
    STAGE_K(0, tile0 * 32);
    asm volatile("s_waitcnt vmcnt(0)" ::: "memory");
    __builtin_amdgcn_s_barrier();
    __builtin_amdgcn_sched_barrier(0);
    STAGE_V(tile0 * 32);
    if (ntiles > 1) STAGE_K(1, (tile0 + 1) * 32);
    __builtin_amdgcn_sched_barrier(0);

    for (int it = 0; it < ntiles; ++it) {
        const u16* Kc = smem + (it & 1) * 8192;
        const u16* Vc = smem + 16384;

        f32x4 S[2];
        S[0] = f32x4{0.f, 0.f, 0.f, 0.f};
        S[1] = f32x4{0.f, 0.f, 0.f, 0.f};
        __builtin_amdgcn_s_setprio(1);
#pragma unroll
        for (int kc = 0; kc < 8; ++kc) {
#pragma unroll
            for (int kn = 0; kn < 2; ++kn) {
                const int r2 = kn * 16 + l16;
                const f16x8 kf = *(const f16x8*)
                    &Kc[r2 * 256 + (((kc * 4 + quad) ^ (l16 & 7)) * 8)];
                S[kn] = MFMA_F16(kf, qf[kc], S[kn], 0, 0, 0);
            }
        }
        __builtin_amdgcn_s_setprio(0);

        float mt = fmaxf(fmaxf(fmaxf(S[0][0], S[0][1]), fmaxf(S[0][2], S[0][3])),
                         fmaxf(fmaxf(S[1][0], S[1][1]), fmaxf(S[1][2], S[1][3])));
        mt = fmaxf(mt, __shfl_xor(mt, 16));
        mt = fmaxf(mt, __shfl_xor(mt, 32));
        // T13 defer-max: rescale only when tile max grows past mrow+8.
        if (__any(mt - mrow > 8.f)) {
            const float mnew = fmaxf(mrow, mt);
            const float a = __expf(mrow - mnew);
            lrow *= a;
#pragma unroll
            for (int dv = 0; dv < 16; ++dv)
#pragma unroll
                for (int r = 0; r < 4; ++r) O[dv][r] *= a;
            mrow = mnew;
        }
        f16x8 pfv;
        float s = 0.f;
#pragma unroll
        for (int kn = 0; kn < 2; ++kn)
#pragma unroll
            for (int r = 0; r < 4; ++r) {
                const float e = __expf(S[kn][r] - mrow);
                s += e;
                pfv[kn * 4 + r] = (_Float16)e;
            }
        s += __shfl_xor(s, 16);
        s += __shfl_xor(s, 32);
        lrow += s;

        // V(t) ready? counted: [V(t)(4), K(t+1)(4 if issued)] outstanding
        if (it + 1 < ntiles) {
            asm volatile("s_waitcnt vmcnt(4)" ::: "memory");
        } else {
            asm volatile("s_waitcnt vmcnt(0)" ::: "memory");
        }
        __builtin_amdgcn_s_barrier();        // V writes visible to all waves
        __builtin_amdgcn_sched_barrier(0);

        __builtin_amdgcn_s_setprio(1);
#pragma unroll
        for (int dvt = 0; dvt < 16; ++dvt) {
            const f16x8 vf = *(const f16x8*)&Vc[dvt * 512 + vbase];
            O[dvt] = MFMA_F16(vf, pfv, O[dvt], 0, 0, 0);
        }
        __builtin_amdgcn_s_setprio(0);

        asm volatile("s_waitcnt vmcnt(0)" ::: "memory");  // K(t+1) complete
        __builtin_amdgcn_s_barrier();        // K visible; V buffer free
        __builtin_amdgcn_sched_barrier(0);
        if (it + 1 < ntiles) {
            STAGE_V((tile0 + it + 1) * 32);                // oldest first
            if (it + 2 < ntiles) STAGE_K(it & 1, (tile0 + it + 2) * 32);
        }
        __builtin_amdgcn_sched_barrier(0);
    }
#undef STAGE_K
#undef STAGE_V

    __syncthreads();   // all waves done with last tile before smem reuse
    {
        const float rl = 1.0f / lrow;
#pragma unroll
        for (int dvt = 0; dvt < 16; ++dvt) {
            ushort4 h4;
            h4.x = f2h(O[dvt][0] * rl);
            h4.y = f2h(O[dvt][1] * rl);
            h4.z = f2h(O[dvt][2] * rl);
            h4.w = f2h(O[dvt][3] * rl);
            *(ushort4*)&Os[(w * 16 + l16) * 264 + dvt * 16 + quad * 4] = h4;
        }
        if (quad == 0) {
            const int grow = b * 2048 + q0 + w * 16 + l16;
            lmpL[z * 16384 + grow] = lrow;
            lmpM[z * 16384 + grow] = mrow;
        }
    }
    __syncthreads();

    {
        const int row = t >> 2;
        if (z < 2) {
            u16* __restrict__ Oz = Op + (size_t)z * 4194304;
#pragma unroll
            for (int i = 0; i < 8; ++i) {
                const int chunk = (t & 3) * 8 + i;
                *(int4*)&Oz[(size_t)(b * 2048 + q0 + row) * 256 + chunk * 8] =
                    *(const int4*)&Os[row * 264 + chunk * 8];
            }
        } else {
            // z==2 packed into d_out scratch: row m -> u16[m*512 + 0..255]
            u16* __restrict__ Oz = OutS;
#pragma unroll
            for (int i = 0; i < 8; ++i) {
                const int chunk = (t & 3) * 8 + i;
                *(int4*)&Oz[(size_t)(b * 2048 + q0 + row) * 512 + chunk * 8] =
                    *(const int4*)&Os[row * 264 + chunk * 8];
            }
        }
    }
}

// ---------------------------------------------------------------------------
// Kernel 3: combine 3 partials + out projection + LayerNorm + LeakyReLU.
// (R24 pipelined version, measured good — UNCHANGED.)
// ---------------------------------------------------------------------------
__global__ __launch_bounds__(256, 2) void outproj_ln(
    const u16* __restrict__ Op, const u16* __restrict__ OutS,
    const float* __restrict__ lmpL, const float* __restrict__ lmpM,
    const u16* __restrict__ Woh, const float* __restrict__ bo,
    const float* __restrict__ gamma, const float* __restrict__ beta,
    float* __restrict__ out)
{
    const int m0   = blockIdx.x * 32;
    const int t    = threadIdx.x;
    const int w    = t >> 6;
    const int rw   = w & 1;        // row-group (16 rows)
    const int cw   = w >> 1;       // col-half (128 cols)
    const int lane = t & 63;
    const int quad = lane >> 4;
    const int l16  = lane & 15;

    // [Ws0 8192][Ws1 8192][Ls0 1024][Ls1 1024] u16 = 36864 B
    __shared__ __align__(16) u16 smem[18432];
    __shared__ _Float16 wls[3][32];
    __shared__ float part[2][16][2][2];   // [rw][row16][cw][{sh,sh2}]

    // W staging source indices (tile-invariant, u16; proj-proven swizzle)
    unsigned wsrc[4];
#pragma unroll
    for (int i = 0; i < 4; ++i) {
        const int j = i * 256 + t;
        const int row = j >> 2, p = j & 3;
        wsrc[i] = (unsigned)(row * 256 + ((p ^ ((row >> 1) & 3)) * 8));
    }
#define OSTAGE_W(bufsel, kc_) do {                                           \
        u16* B_ = smem + (bufsel) * 8192;                                    \
        _Pragma("unroll")                                                    \
        for (int i_ = 0; i_ < 4; ++i_)                                       \
            gl16(Woh + wsrc[i_] + (unsigned)(kc_) * 32,                      \
                 B_ + i_ * 2048 + w * 512);                                  \
    } while (0)

    const int prow = t >> 2, pcg = t & 3;   // partial row/chunk (t<128 active)
    const unsigned lsw = (unsigned)(prow * 32 + ((pcg ^ ((prow >> 1) & 3)) * 8));

    // prologue: stage W(0) + load partials(0) (latency overlaps wls barrier)
    OSTAGE_W(0, 0);
    int4 po0, po1, po2;
    if (t < 128) {
        const size_t off  = (size_t)(m0 + prow) * 256 + pcg * 8;
        const size_t offS = (size_t)(m0 + prow) * 512 + pcg * 8;
        po0 = *(const int4*)&Op[off];
        po1 = *(const int4*)&Op[4194304 + off];
        po2 = *(const int4*)&OutS[offS];
    }

    if (t < 32) {
        const float l0 = lmpL[m0 + t];
        const float l1 = lmpL[16384 + m0 + t];
        const float l2 = lmpL[32768 + m0 + t];
        const float m0v = lmpM[m0 + t];
        const float m1v = lmpM[16384 + m0 + t];
        const float m2v = lmpM[32768 + m0 + t];
        const float mm = fmaxf(fmaxf(m0v, m1v), m2v);
        const float u0 = l0 * __expf(m0v - mm);
        const float u1 = l1 * __expf(m1v - mm);
        const float u2 = l2 * __expf(m2v - mm);
        const float inv = 1.0f / (u0 + u1 + u2);
        wls[0][t] = (_Float16)(u0 * inv);
        wls[1][t] = (_Float16)(u1 * inv);
        wls[2][t] = (_Float16)(u2 * inv);
    }
    __syncthreads();   // wls visible (prologue-only full drain is fine)

    if (t < 128) {
        const _Float16 w0 = wls[0][prow], w1 = wls[1][prow], w2 = wls[2][prow];
        const f16x8 o0 = __builtin_bit_cast(f16x8, po0);
        const f16x8 o1 = __builtin_bit_cast(f16x8, po1);
        const f16x8 o2 = __builtin_bit_cast(f16x8, po2);
        f16x8 lw;
#pragma unroll
        for (int j = 0; j < 8; ++j)
            lw[j] = o0[j] * w0 + o1[j] * w1 + o2[j] * w2;
        *(int4*)&smem[16384 + lsw] = __builtin_bit_cast(int4, lw);   // Ls0
    }

    f32x4 acc[8];
#pragma unroll
    for (int i = 0; i < 8; ++i) acc[i] = f32x4{0.f, 0.f, 0.f, 0.f};

    const int rp = (quad ^ ((l16 >> 1) & 3)) * 8;   // swizzled read offset

    for (int kc = 0; kc < 8; ++kc) {
        asm volatile("s_waitcnt vmcnt(0)" ::: "memory");
        __builtin_amdgcn_s_barrier();       // W(kc) in LDS; Ls(kc) visible
        __builtin_amdgcn_sched_barrier(0);
        if (kc + 1 < 8) {
            OSTAGE_W((kc + 1) & 1, kc + 1);
            if (t < 128) {
                const size_t off  = (size_t)(m0 + prow) * 256 + (kc + 1) * 32 + pcg * 8;
                const size_t offS = (size_t)(m0 + prow) * 512 + (kc + 1) * 32 + pcg * 8;
                po0 = *(const int4*)&Op[off];
                po1 = *(const int4*)&Op[4194304 + off];
                po2 = *(const int4*)&OutS[offS];
            }
        }
        __builtin_amdgcn_sched_barrier(0);

        const u16* Wb = smem + (kc & 1) * 8192;
        const u16* Lb = smem + 16384 + (kc & 1) * 1024;

        const f16x8 af = *(const f16x8*)&Lb[(rw * 16 + l16) * 32 + rp];
        __builtin_amdgcn_s_setprio(1);
#pragma unroll
        for (int nt = 0; nt < 8; ++nt) {
            const f16x8 bf = *(const f16x8*)&Wb[((cw * 8 + nt) * 16 + l16) * 32 + rp];
            acc[nt] = MFMA_F16(af, bf, acc[nt], 0, 0, 0);
        }
        __builtin_amdgcn_s_setprio(0);

        if (kc + 1 < 8 && t < 128) {
            const _Float16 w0 = wls[0][prow], w1 = wls[1][prow], w2 = wls[2][prow];
            const f16x8 o0 = __builtin_bit_cast(f16x8, po0);
            const f16x8 o1 = __builtin_bit_cast(f16x8, po1);
            const f16x8 o2 = __builtin_bit_cast(f16x8, po2);
            f16x8 lw;
#pragma unroll
            for (int j = 0; j < 8; ++j)
                lw[j] = o0[j] * w0 + o1[j] * w1 + o2[j] * w2;
            *(int4*)&smem[16384 + ((kc + 1) & 1) * 1024 + lsw] =
                __builtin_bit_cast(int4, lw);
        }
    }
#undef OSTAGE_W

    float g[8], bt[8], bb[8];
#pragma unroll
    for (int nt = 0; nt < 8; ++nt) {
        const int col = cw * 128 + nt * 16 + l16;
        bb[nt] = bo[col]; g[nt] = gamma[col]; bt[nt] = beta[col];
    }

    float shv[4], sh2v[4];
#pragma unroll
    for (int r = 0; r < 4; ++r) {
        float sh = 0.f, sh2 = 0.f;
#pragma unroll
        for (int nt = 0; nt < 8; ++nt) {
            const float h = acc[nt][r] + bb[nt];
            sh  += h;
            sh2 += h * h;
        }
        sh  += __shfl_xor(sh, 1);  sh  += __shfl_xor(sh, 2);
        sh  += __shfl_xor(sh, 4);  sh  += __shfl_xor(sh, 8);
        sh2 += __shfl_xor(sh2, 1); sh2 += __shfl_xor(sh2, 2);
        sh2 += __shfl_xor(sh2, 4); sh2 += __shfl_xor(sh2, 8);
        shv[r] = sh; sh2v[r] = sh2;
    }
    if (l16 == 0) {
#pragma unroll
        for (int r = 0; r < 4; ++r) {
            part[rw][quad * 4 + r][cw][0] = shv[r];
            part[rw][quad * 4 + r][cw][1] = sh2v[r];
        }
    }
    __syncthreads();

#pragma unroll
    for (int r = 0; r < 4; ++r) {
        const float sh  = shv[r]  + part[rw][quad * 4 + r][cw ^ 1][0];
        const float sh2 = sh2v[r] + part[rw][quad * 4 + r][cw ^ 1][1];
        const float mu  = sh * (1.f / 256.f);
        const float var = fmaxf(sh2 * (1.f / 256.f) - mu * mu, 0.f);
        const float rs  = rsqrtf(var + 1e-5f);
        const size_t row = (size_t)(m0 + rw * 16 + quad * 4 + r) * 256;
#pragma unroll
        for (int nt = 0; nt < 8; ++nt) {
            const float hn = (acc[nt][r] + bb[nt] - mu) * rs * g[nt] + bt[nt];
            out[row + cw * 128 + nt * 16 + l16] = (hn >= 0.f) ? hn : 0.01f * hn;
        }
    }
}

// ---------------------------------------------------------------------------
extern "C" void kernel_launch(void* const* d_in, const int* in_sizes, int n_in,
                              void* d_out, int out_size, void* d_ws, size_t ws_size,
                              hipStream_t stream)
{
    const float* x  = (const float*)d_in[0];
    const float* Wq = (const float*)d_in[1];
    const float* bq = (const float*)d_in[2];
    const float* Wk = (const float*)d_in[3];
    const float* bk = (const float*)d_in[4];
    const float* Wv = (const float*)d_in[5];
    const float* bv = (const float*)d_in[6];
    const float* Wo = (const float*)d_in[7];
    const float* bo = (const float*)d_in[8];
    const float* gm = (const float*)d_in[9];
    const float* bt = (const float*)d_in[10];
    float* out = (float*)d_out;

    // ws layout (u16): [W4 262144][Qh 4.19M][Kh 4.19M][Vt 4.19M][Op 2x4.19M][lmpM]
    // -> identical total d_ws footprint to the baseline.
    // d_out scratch lifecycle (Xh pass eliminated in R25): attn writes the
    // z=2 partial into d_out; outproj reads it (rows read before overwritten,
    // block-local) and writes the final f32 output.
    // l[3] stats in dead Wq/Wk/Wv half of W4 (384KB, dead after proj);
    // m[3] stats in the old lmp slot.
    u16* W4 = (u16*)d_ws;
    u16* Qh = W4 + 262144;
    u16* Kh = Qh + 4194304;
    u16* Vt = Kh + 4194304;
    u16* Op = Vt + 4194304;
    float* lmpM = (float*)(Op + 2 * 4194304);  // m[3][16384]
    float* lmpL = (float*)W4;                  // l[3][16384] (dead W region)
    u16* Woh = W4 + 196608;
    u16* OutS = (u16*)d_out;

    prep_w     <<<64,             256, 0, stream>>>(Wq, Wk, Wv, Wo, W4);
    proj_qkv   <<<dim3(256, 3),   256, 0, stream>>>(x, W4, bq, bk, bv, Qh, Kh, Vt);
    attn       <<<dim3(32, 8, 3), 256, 0, stream>>>(Qh, Kh, Vt, Op, OutS, lmpL, lmpM);
    outproj_ln <<<512,            256, 0, stream>>>(Op, OutS, lmpL, lmpM, Woh, bo, gm, bt, out);
}